// Round 15
// baseline (497.334 us; speedup 1.0000x reference)
//
#include <hip/hip_runtime.h>
#include <hip/hip_cooperative_groups.h>
#include <stdint.h>

namespace cg = cooperative_groups;

#define N_NODES  8192
#define HIDDEN   256
#define HEADS    4
#define HEAD_DIM 64
#define NUM_EDGES 4096
#define NUM_INC  65536
#define LN_EPS   1e-5f

typedef unsigned int uint_t;
typedef float __attribute__((ext_vector_type(4))) f4v;

// Inputs fp32, OUTPUTS fp32 (r11-r14 verified, absmax 0.0156).
// r14 model: ~225us harness poison/restore; kernel share ~143us. This round:
// prefix chain (7 launch boundaries) -> 1 cooperative kernel w/ grid.sync.

// ---------------- ws layout (bytes) ----------------
#define OFF_SEGSZ    0        // int [4096]   } zeroed in phase Z
#define OFF_NCNT     16384    // int [8192]   }
#define OFF_NFILL    49152    // int [8192]   }
#define OFF_EFILL    81920    // int [4096]   }
#define ZERO_BYTES   98304
#define OFF_VKH      98304    // float [4*256] transposed [h][k]
#define OFF_BL       102400   // float [pad]
#define OFF_LOGIT    102464   // float [8192*4]
#define OFF_NPTR     233536   // int [8193] (+pad)
#define OFF_EPTR     266320   // int [4097] (+pad)
#define OFF_SEGSUM   282720   // float [4096*4]
#define OFF_NINC     348256   // int [65536]
#define OFF_EMEM     610400   // int [65536]
#define OFF_ITEM     872544   // float4 [65536] = {attn, qb, qe, 0}

// K1 (cooperative, 256 blocks): entire preprocessing pipeline, 6 phases.
__global__ __launch_bounds__(256) void k_prep(
    const float* __restrict__ x,
    const int* __restrict__ node_idx,
    const int* __restrict__ edge_idx,
    const float* __restrict__ Ww,
    const float* __restrict__ Wb,
    const float* __restrict__ ea,
    uint_t* __restrict__ ws_zero,
    float* __restrict__ vkhT,
    float* __restrict__ bl,
    float* __restrict__ logit,
    int* __restrict__ seg_size,
    int* __restrict__ node_cnt,
    int* __restrict__ node_ptr,
    int* __restrict__ edge_ptr,
    int* __restrict__ node_fill,
    int* __restrict__ edge_fill,
    int* __restrict__ node_inc,
    int* __restrict__ edge_mem,
    float* __restrict__ seg_sum,
    float4* __restrict__ item)
{
    cg::grid_group grid = cg::this_grid();
    int t = threadIdx.x, b = blockIdx.x;

    __shared__ __align__(16) float xs[32 * HIDDEN];    // 32 KB
    __shared__ __align__(16) float vs[HEADS * HIDDEN]; // 4 KB
    __shared__ float bls[HEADS];
    __shared__ int part[256];

    // ---- Z: zero accumulators (24576 words over 256 blocks = 96/block);
    //         blocks 0..3 also fold W_w/W_b with edge_att ----
    if (t < 96) ws_zero[b * 96 + t] = 0u;
    if (b < HEADS) {
        int k = t, h = b;
        float a = 0.f;
        for (int d = 0; d < HEAD_DIM; ++d)
            a += ea[h * HEAD_DIM + d] * Ww[(size_t)(h * HEAD_DIM + d) * HIDDEN + k];
        vkhT[h * HIDDEN + k] = a;
        if (k == 0) {
            float s = 0.f;
            for (int d = 0; d < HEAD_DIM; ++d)
                s += Wb[h * HEAD_DIM + d] * ea[h * HEAD_DIM + d];
            bl[h] = s;
        }
    }
    grid.sync();

    // ---- L: logits, block covers nodes b*32..b*32+31 ----
    {
        float4* xsv = (float4*)xs;
        const float4* xg = (const float4*)(x + (size_t)b * 32 * HIDDEN);
        #pragma unroll
        for (int i = 0; i < 8; ++i) xsv[i * 256 + t] = xg[i * 256 + t];
        ((float4*)vs)[t] = ((const float4*)vkhT)[t];
        if (t < HEADS) bls[t] = bl[t];
        __syncthreads();
        if (t < 128) {
            int n = t >> 2, h = t & 3;
            const float4* xr = (const float4*)(xs + n * HIDDEN);
            const float4* vr = (const float4*)(vs + h * HIDDEN);
            float acc = bls[h];
            for (int k4 = 0; k4 < HIDDEN / 4; ++k4) {
                float4 xv = xr[k4], vv = vr[k4];
                acc += xv.x * vv.x + xv.y * vv.y + xv.z * vv.z + xv.w * vv.w;
            }
            logit[(b * 32 + n) * HEADS + h] = acc;
        }
    }
    // ---- C: histogram counts (independent of logits; no sync needed before) ----
    {
        int i = b * 256 + t;
        atomicAdd(&seg_size[edge_idx[i]], 1);
        atomicAdd(&node_cnt[node_idx[i]], 1);
    }
    grid.sync();

    // ---- S: exclusive scans (blocks 0: nodes, 1: edges) ----
    if (b < 2) {
        const int* cnt = (b == 0) ? node_cnt : seg_size;
        int* ptr = (b == 0) ? node_ptr : edge_ptr;
        int n = (b == 0) ? N_NODES : NUM_EDGES;
        int C = n / 256;
        int s = 0;
        for (int j = 0; j < C; ++j) s += cnt[t * C + j];
        part[t] = s;
        __syncthreads();
        if (t == 0) {
            int run = 0;
            for (int i = 0; i < 256; ++i) { int tmp = part[i]; part[i] = run; run += tmp; }
            ptr[n] = run;
        }
        __syncthreads();
        int run = part[t];
        for (int j = 0; j < C; ++j) { ptr[t * C + j] = run; run += cnt[t * C + j]; }
    }
    grid.sync();

    // ---- F: fill CSRs ----
    {
        int i = b * 256 + t;
        int n = node_idx[i], e = edge_idx[i];
        int p = node_ptr[n] + atomicAdd(&node_fill[n], 1);
        node_inc[p] = i;
        int q = edge_ptr[e] + atomicAdd(&edge_fill[e], 1);
        edge_mem[q] = n;
    }
    grid.sync();

    // ---- G: seg_sum gather (16 edges per block) ----
    if (t < 16) {
        int e = b * 16 + t;
        int qb = edge_ptr[e], qe = edge_ptr[e + 1];
        float s0 = 0, s1 = 0, s2 = 0, s3 = 0;
        for (int q = qb; q < qe; ++q) {
            int j = edge_mem[q];
            s0 += __expf(logit[j * 4 + 0]);
            s1 += __expf(logit[j * 4 + 1]);
            s2 += __expf(logit[j * 4 + 2]);
            s3 += __expf(logit[j * 4 + 3]);
        }
        seg_sum[e * 4 + 0] = s0; seg_sum[e * 4 + 1] = s1;
        seg_sum[e * 4 + 2] = s2; seg_sum[e * 4 + 3] = s3;
    }
    grid.sync();

    // ---- P: aw_item[p] = {attn, qb, qe, 0} in node-CSR order ----
    {
        int p = b * 256 + t;
        int m = node_inc[p];
        int e = edge_idx[m];
        int qb = edge_ptr[e], qe = edge_ptr[e + 1];
        float a = 0.f;
        if (qe - qb >= 2) {
            int n = node_idx[m];
            float s = 0.f;
            #pragma unroll
            for (int h = 0; h < HEADS; ++h)
                s += __expf(logit[n * HEADS + h]) / seg_sum[e * HEADS + h];
            a = 0.25f * s;
        }
        float4 it;
        it.x = a;
        it.y = __int_as_float(qb);
        it.z = __int_as_float(qe);
        it.w = 0.f;
        item[p] = it;
    }
}

// K2 (fused, r14-proven): every block builds+stores AW row; blocks 0..511
// then reuse the 32KB LDS as the 16-row out0 tile (GEMM + wave-parallel LN).
__global__ __launch_bounds__(256) void k_aw_out(const float4* __restrict__ item,
                                                const int* __restrict__ node_ptr,
                                                const int* __restrict__ edge_mem,
                                                const float* __restrict__ x,
                                                const float* __restrict__ out_w,
                                                const float* __restrict__ out_b,
                                                float* __restrict__ AW,
                                                float* __restrict__ out0) {
    __shared__ __align__(16) float buf[N_NODES];   // 32 KB
    __shared__ float sr[16], mu_s[16], rs_s[16];
    int t = threadIdx.x, w = t >> 6, lane = t & 63;
    int i = blockIdx.x;

    float4* rowv = (float4*)buf;
    #pragma unroll
    for (int c = 0; c < 8; ++c) rowv[c * 256 + t] = make_float4(0.f, 0.f, 0.f, 0.f);
    __syncthreads();
    int pb = node_ptr[i], pe = node_ptr[i + 1];
    for (int p = pb + w; p < pe; p += 4) {
        float4 it = item[p];
        float a = it.x;
        if (a != 0.f) {
            int qb = __float_as_int(it.y), qe = __float_as_int(it.z);
            for (int q = qb + lane; q < qe; q += 64)
                atomicAdd(&buf[edge_mem[q]], a);
        }
    }
    __syncthreads();
    if (t == 0) buf[i] = 0.f;
    __syncthreads();
    f4v* dst = (f4v*)(AW + (size_t)i * N_NODES);
    #pragma unroll
    for (int c = 0; c < 8; ++c)
        __builtin_nontemporal_store(((const f4v*)rowv)[c * 256 + t], &dst[c * 256 + t]);

    if (i >= 512) return;

    __syncthreads();
    float (*y)[260] = (float (*)[260])buf;
    int R = i * 16;
    if (t < 16) {
        int n = R + t;
        int nb = node_ptr[n], ne = node_ptr[n + 1];
        float ws = 0.f;
        for (int p = nb; p < ne; ++p) ws += item[p].x;
        int c = ne - nb; if (c < 1) c = 1;
        sr[t] = ws / (float)c;
    }
    __syncthreads();
    #pragma unroll
    for (int r = 0; r < 16; ++r)
        y[r][t] = sr[r] * x[(size_t)(R + r) * HIDDEN + t];
    __syncthreads();
    float acc[16];
    float bias = out_b[t];
    #pragma unroll
    for (int r = 0; r < 16; ++r) acc[r] = bias;
    const float4* wr4 = (const float4*)(out_w + (size_t)t * HIDDEN);
    for (int j4 = 0; j4 < HIDDEN / 4; ++j4) {
        float4 wv = wr4[j4];
        #pragma unroll
        for (int r = 0; r < 16; ++r) {
            float4 yv = *(const float4*)&y[r][j4 * 4];
            acc[r] += yv.x * wv.x + yv.y * wv.y + yv.z * wv.z + yv.w * wv.w;
        }
    }
    __syncthreads();
    #pragma unroll
    for (int r = 0; r < 16; ++r) y[r][t] = acc[r];
    __syncthreads();
    #pragma unroll
    for (int rr = 0; rr < 4; ++rr) {
        int r = (w << 2) | rr;
        float v = y[r][lane] + y[r][lane + 64] + y[r][lane + 128] + y[r][lane + 192];
        #pragma unroll
        for (int off = 32; off; off >>= 1) v += __shfl_down(v, off, 64);
        float mu = __shfl(v, 0, 64) * (1.0f / HIDDEN);
        float d0 = y[r][lane] - mu, d1 = y[r][lane + 64] - mu;
        float d2 = y[r][lane + 128] - mu, d3 = y[r][lane + 192] - mu;
        float s2 = d0 * d0 + d1 * d1 + d2 * d2 + d3 * d3;
        #pragma unroll
        for (int off = 32; off; off >>= 1) s2 += __shfl_down(s2, off, 64);
        if (lane == 0) {
            mu_s[r] = mu;
            rs_s[r] = rsqrtf(s2 * (1.0f / HIDDEN) + LN_EPS);
        }
    }
    __syncthreads();
    #pragma unroll
    for (int r = 0; r < 16; ++r)
        out0[(size_t)(R + r) * HIDDEN + t] = (y[r][t] - mu_s[r]) * rs_s[r];
}

extern "C" void kernel_launch(void* const* d_in, const int* in_sizes, int n_in,
                              void* d_out, int out_size, void* d_ws, size_t ws_size,
                              hipStream_t stream) {
    const float* x        = (const float*)d_in[0];
    const int*   node_idx = (const int*)d_in[1];
    const int*   edge_idx = (const int*)d_in[2];
    const float* Ww       = (const float*)d_in[3];
    const float* Wb       = (const float*)d_in[4];
    const float* ea       = (const float*)d_in[5];
    const float* ow       = (const float*)d_in[6];
    const float* ob       = (const float*)d_in[7];
    float* out0 = (float*)d_out;
    float* aw   = out0 + (size_t)N_NODES * HIDDEN;

    char* ws = (char*)d_ws;
    uint_t* ws_zero   = (uint_t*)ws;
    int*    seg_size  = (int*)(ws + OFF_SEGSZ);
    int*    node_cnt  = (int*)(ws + OFF_NCNT);
    int*    node_fill = (int*)(ws + OFF_NFILL);
    int*    edge_fill = (int*)(ws + OFF_EFILL);
    float*  vkhT      = (float*)(ws + OFF_VKH);
    float*  bl        = (float*)(ws + OFF_BL);
    float*  logit     = (float*)(ws + OFF_LOGIT);
    int*    node_ptr  = (int*)(ws + OFF_NPTR);
    int*    edge_ptr  = (int*)(ws + OFF_EPTR);
    float*  seg_sum   = (float*)(ws + OFF_SEGSUM);
    int*    node_inc  = (int*)(ws + OFF_NINC);
    int*    edge_mem  = (int*)(ws + OFF_EMEM);
    float4* item      = (float4*)(ws + OFF_ITEM);

    void* args[] = { (void*)&x, (void*)&node_idx, (void*)&edge_idx, (void*)&Ww,
                     (void*)&Wb, (void*)&ea, (void*)&ws_zero, (void*)&vkhT,
                     (void*)&bl, (void*)&logit, (void*)&seg_size, (void*)&node_cnt,
                     (void*)&node_ptr, (void*)&edge_ptr, (void*)&node_fill,
                     (void*)&edge_fill, (void*)&node_inc, (void*)&edge_mem,
                     (void*)&seg_sum, (void*)&item };
    hipLaunchCooperativeKernel((const void*)k_prep, dim3(256), dim3(256),
                               args, 0, stream);
    k_aw_out<<<N_NODES, 256, 0, stream>>>(item, node_ptr, edge_mem, x, ow, ob, aw, out0);
}

// Round 16
// 367.705 us; speedup vs baseline: 1.3525x; 1.3525x over previous
//
#include <hip/hip_runtime.h>
#include <stdint.h>

#define N_NODES  8192
#define HIDDEN   256
#define HEADS    4
#define HEAD_DIM 64
#define NUM_EDGES 4096
#define NUM_INC  65536
#define LN_EPS   1e-5f

typedef unsigned int uint_t;
typedef float __attribute__((ext_vector_type(4))) f4v;

// Inputs fp32, OUTPUTS fp32 (r11-r14 verified, absmax 0.0156).
// r15 lesson: grid.sync() ~24us each on this harness — launch boundaries
// (~3us) are cheaper. Structure = r14 (368us proven) with k_pass1's
// independent histogram atomics folded into k_logits (latency hidden
// behind the FMA loop). 7 dispatches.

// ---------------- ws layout (bytes) ----------------
#define OFF_SEGSZ    0        // int [4096]   } zeroed by k_foldzero
#define OFF_NCNT     16384    // int [8192]   }
#define OFF_NFILL    49152    // int [8192]   }
#define OFF_EFILL    81920    // int [4096]   }
#define ZERO_BYTES   98304
#define OFF_VKH      98304    // float [4*256] transposed [h][k]
#define OFF_BL       102400   // float [pad]
#define OFF_LOGIT    102464   // float [8192*4]
#define OFF_NPTR     233536   // int [8193] (+pad)
#define OFF_EPTR     266320   // int [4097] (+pad)
#define OFF_SEGSUM   282720   // float [4096*4]
#define OFF_NINC     348256   // int [65536]
#define OFF_EMEM     610400   // int [65536]
#define OFF_ITEM     872544   // float4 [65536] = {attn, qb, qe, 0}

// K1: zero accumulators (96 blocks); blocks 0..3 also fold W_w/W_b with ea.
__global__ __launch_bounds__(256) void k_foldzero(const float* __restrict__ Ww,
                                                  const float* __restrict__ Wb,
                                                  const float* __restrict__ ea,
                                                  float* __restrict__ vkhT,
                                                  float* __restrict__ bl,
                                                  uint_t* __restrict__ zw) {
    int t = threadIdx.x, b = blockIdx.x;
    zw[b * 256 + t] = 0u;
    if (b < HEADS) {
        int k = t, h = b;
        float a = 0.f;
        for (int d = 0; d < HEAD_DIM; ++d)
            a += ea[h * HEAD_DIM + d] * Ww[(size_t)(h * HEAD_DIM + d) * HIDDEN + k];
        vkhT[h * HIDDEN + k] = a;
        if (k == 0) {
            float s = 0.f;
            for (int d = 0; d < HEAD_DIM; ++d)
                s += Wb[h * HEAD_DIM + d] * ea[h * HEAD_DIM + d];
            bl[h] = s;
        }
    }
}

// K2: logits (256 blocks x 32 nodes) + independent histogram atomics folded in
// (they depend only on idx arrays + zeroed counters; issue early, complete
// in the shadow of the FMA loop).
__global__ __launch_bounds__(256) void k_logits(const float* __restrict__ x,
                                                const float* __restrict__ vkhT,
                                                const float* __restrict__ bl,
                                                const int* __restrict__ node_idx,
                                                const int* __restrict__ edge_idx,
                                                int* __restrict__ seg_size,
                                                int* __restrict__ node_cnt,
                                                float* __restrict__ logit) {
    __shared__ __align__(16) float xs[32 * HIDDEN];
    __shared__ __align__(16) float vs[HEADS * HIDDEN];
    __shared__ float bls[HEADS];
    int t = threadIdx.x, b = blockIdx.x;
    // histogram (one incidence per thread, grid covers all 65536)
    {
        int i = b * 256 + t;
        atomicAdd(&seg_size[edge_idx[i]], 1);
        atomicAdd(&node_cnt[node_idx[i]], 1);
    }
    float4* xsv = (float4*)xs;
    const float4* xg = (const float4*)(x + (size_t)b * 32 * HIDDEN);
    #pragma unroll
    for (int i = 0; i < 8; ++i) xsv[i * 256 + t] = xg[i * 256 + t];
    ((float4*)vs)[t] = ((const float4*)vkhT)[t];
    if (t < HEADS) bls[t] = bl[t];
    __syncthreads();
    if (t < 128) {
        int n = t >> 2, h = t & 3;
        const float4* xr = (const float4*)(xs + n * HIDDEN);
        const float4* vr = (const float4*)(vs + h * HIDDEN);
        float acc = bls[h];
        for (int k4 = 0; k4 < HIDDEN / 4; ++k4) {
            float4 xv = xr[k4], vv = vr[k4];
            acc += xv.x * vv.x + xv.y * vv.y + xv.z * vv.z + xv.w * vv.w;
        }
        logit[(b * 32 + n) * HEADS + h] = acc;
    }
}

// K3: exclusive scans
__global__ __launch_bounds__(256) void k_scan(const int* __restrict__ node_cnt, int* __restrict__ node_ptr,
                                              const int* __restrict__ seg_size, int* __restrict__ edge_ptr) {
    __shared__ int part[256];
    const int* cnt; int* ptr; int n;
    if (blockIdx.x == 0) { cnt = node_cnt; ptr = node_ptr; n = N_NODES; }
    else                 { cnt = seg_size; ptr = edge_ptr; n = NUM_EDGES; }
    int t = threadIdx.x, C = n / 256;
    int s = 0;
    for (int j = 0; j < C; ++j) s += cnt[t * C + j];
    part[t] = s;
    __syncthreads();
    if (t == 0) {
        int run = 0;
        for (int i = 0; i < 256; ++i) { int tmp = part[i]; part[i] = run; run += tmp; }
        ptr[n] = run;
    }
    __syncthreads();
    int run = part[t];
    for (int j = 0; j < C; ++j) { ptr[t * C + j] = run; run += cnt[t * C + j]; }
}

// K4: fill CSRs
__global__ void k_fill(const int* __restrict__ node_idx, const int* __restrict__ edge_idx,
                       const int* __restrict__ node_ptr, const int* __restrict__ edge_ptr,
                       int* __restrict__ node_fill, int* __restrict__ edge_fill,
                       int* __restrict__ node_inc, int* __restrict__ edge_mem) {
    int i = blockIdx.x * 256 + threadIdx.x;
    int n = node_idx[i], e = edge_idx[i];
    int p = node_ptr[n] + atomicAdd(&node_fill[n], 1);
    node_inc[p] = i;
    int q = edge_ptr[e] + atomicAdd(&edge_fill[e], 1);
    edge_mem[q] = n;
}

// K5: seg_sum by edge-parallel gather
__global__ __launch_bounds__(256) void k_seg(const int* __restrict__ edge_ptr,
                                             const int* __restrict__ edge_mem,
                                             const float* __restrict__ logit,
                                             float* __restrict__ seg_sum) {
    int e = blockIdx.x * 256 + threadIdx.x;
    int qb = edge_ptr[e], qe = edge_ptr[e + 1];
    float s0 = 0, s1 = 0, s2 = 0, s3 = 0;
    for (int q = qb; q < qe; ++q) {
        int j = edge_mem[q];
        s0 += __expf(logit[j * 4 + 0]);
        s1 += __expf(logit[j * 4 + 1]);
        s2 += __expf(logit[j * 4 + 2]);
        s3 += __expf(logit[j * 4 + 3]);
    }
    seg_sum[e * 4 + 0] = s0; seg_sum[e * 4 + 1] = s1;
    seg_sum[e * 4 + 2] = s2; seg_sum[e * 4 + 3] = s3;
}

// K6: aw_item[p] = {attn, qb, qe, 0} in node-CSR order
__global__ __launch_bounds__(256) void k_pairs(const int* __restrict__ node_inc,
                                               const int* __restrict__ node_idx,
                                               const int* __restrict__ edge_idx,
                                               const int* __restrict__ edge_ptr,
                                               const float* __restrict__ logit,
                                               const float* __restrict__ seg_sum,
                                               float4* __restrict__ item) {
    int p = blockIdx.x * 256 + threadIdx.x;
    int m = node_inc[p];
    int e = edge_idx[m];
    int qb = edge_ptr[e], qe = edge_ptr[e + 1];
    float a = 0.f;
    if (qe - qb >= 2) {
        int n = node_idx[m];
        float s = 0.f;
        #pragma unroll
        for (int h = 0; h < HEADS; ++h)
            s += __expf(logit[n * HEADS + h]) / seg_sum[e * HEADS + h];
        a = 0.25f * s;
    }
    float4 it;
    it.x = a;
    it.y = __int_as_float(qb);
    it.z = __int_as_float(qe);
    it.w = 0.f;
    item[p] = it;
}

// K7 (fused, r14-proven): every block builds+stores AW row; blocks 0..511
// then reuse the 32KB LDS as the 16-row out0 tile (GEMM + wave-parallel LN).
__global__ __launch_bounds__(256) void k_aw_out(const float4* __restrict__ item,
                                                const int* __restrict__ node_ptr,
                                                const int* __restrict__ edge_mem,
                                                const float* __restrict__ x,
                                                const float* __restrict__ out_w,
                                                const float* __restrict__ out_b,
                                                float* __restrict__ AW,
                                                float* __restrict__ out0) {
    __shared__ __align__(16) float buf[N_NODES];   // 32 KB
    __shared__ float sr[16], mu_s[16], rs_s[16];
    int t = threadIdx.x, w = t >> 6, lane = t & 63;
    int i = blockIdx.x;

    float4* rowv = (float4*)buf;
    #pragma unroll
    for (int c = 0; c < 8; ++c) rowv[c * 256 + t] = make_float4(0.f, 0.f, 0.f, 0.f);
    __syncthreads();
    int pb = node_ptr[i], pe = node_ptr[i + 1];
    for (int p = pb + w; p < pe; p += 4) {
        float4 it = item[p];
        float a = it.x;
        if (a != 0.f) {
            int qb = __float_as_int(it.y), qe = __float_as_int(it.z);
            for (int q = qb + lane; q < qe; q += 64)
                atomicAdd(&buf[edge_mem[q]], a);
        }
    }
    __syncthreads();
    if (t == 0) buf[i] = 0.f;
    __syncthreads();
    f4v* dst = (f4v*)(AW + (size_t)i * N_NODES);
    #pragma unroll
    for (int c = 0; c < 8; ++c)
        __builtin_nontemporal_store(((const f4v*)rowv)[c * 256 + t], &dst[c * 256 + t]);

    if (i >= 512) return;

    __syncthreads();
    float (*y)[260] = (float (*)[260])buf;
    int R = i * 16;
    if (t < 16) {
        int n = R + t;
        int nb = node_ptr[n], ne = node_ptr[n + 1];
        float ws = 0.f;
        for (int p = nb; p < ne; ++p) ws += item[p].x;
        int c = ne - nb; if (c < 1) c = 1;
        sr[t] = ws / (float)c;
    }
    __syncthreads();
    #pragma unroll
    for (int r = 0; r < 16; ++r)
        y[r][t] = sr[r] * x[(size_t)(R + r) * HIDDEN + t];
    __syncthreads();
    float acc[16];
    float bias = out_b[t];
    #pragma unroll
    for (int r = 0; r < 16; ++r) acc[r] = bias;
    const float4* wr4 = (const float4*)(out_w + (size_t)t * HIDDEN);
    for (int j4 = 0; j4 < HIDDEN / 4; ++j4) {
        float4 wv = wr4[j4];
        #pragma unroll
        for (int r = 0; r < 16; ++r) {
            float4 yv = *(const float4*)&y[r][j4 * 4];
            acc[r] += yv.x * wv.x + yv.y * wv.y + yv.z * wv.z + yv.w * wv.w;
        }
    }
    __syncthreads();
    #pragma unroll
    for (int r = 0; r < 16; ++r) y[r][t] = acc[r];
    __syncthreads();
    #pragma unroll
    for (int rr = 0; rr < 4; ++rr) {
        int r = (w << 2) | rr;
        float v = y[r][lane] + y[r][lane + 64] + y[r][lane + 128] + y[r][lane + 192];
        #pragma unroll
        for (int off = 32; off; off >>= 1) v += __shfl_down(v, off, 64);
        float mu = __shfl(v, 0, 64) * (1.0f / HIDDEN);
        float d0 = y[r][lane] - mu, d1 = y[r][lane + 64] - mu;
        float d2 = y[r][lane + 128] - mu, d3 = y[r][lane + 192] - mu;
        float s2 = d0 * d0 + d1 * d1 + d2 * d2 + d3 * d3;
        #pragma unroll
        for (int off = 32; off; off >>= 1) s2 += __shfl_down(s2, off, 64);
        if (lane == 0) {
            mu_s[r] = mu;
            rs_s[r] = rsqrtf(s2 * (1.0f / HIDDEN) + LN_EPS);
        }
    }
    __syncthreads();
    #pragma unroll
    for (int r = 0; r < 16; ++r)
        out0[(size_t)(R + r) * HIDDEN + t] = (y[r][t] - mu_s[r]) * rs_s[r];
}

extern "C" void kernel_launch(void* const* d_in, const int* in_sizes, int n_in,
                              void* d_out, int out_size, void* d_ws, size_t ws_size,
                              hipStream_t stream) {
    const float* x        = (const float*)d_in[0];
    const int*   node_idx = (const int*)d_in[1];
    const int*   edge_idx = (const int*)d_in[2];
    const float* Ww       = (const float*)d_in[3];
    const float* Wb       = (const float*)d_in[4];
    const float* ea       = (const float*)d_in[5];
    const float* ow       = (const float*)d_in[6];
    const float* ob       = (const float*)d_in[7];
    float* out0 = (float*)d_out;
    float* aw   = out0 + (size_t)N_NODES * HIDDEN;

    char* ws = (char*)d_ws;
    int*    seg_size  = (int*)(ws + OFF_SEGSZ);
    int*    node_cnt  = (int*)(ws + OFF_NCNT);
    int*    node_fill = (int*)(ws + OFF_NFILL);
    int*    edge_fill = (int*)(ws + OFF_EFILL);
    float*  vkhT      = (float*)(ws + OFF_VKH);
    float*  bl        = (float*)(ws + OFF_BL);
    float*  logit     = (float*)(ws + OFF_LOGIT);
    int*    node_ptr  = (int*)(ws + OFF_NPTR);
    int*    edge_ptr  = (int*)(ws + OFF_EPTR);
    float*  seg_sum   = (float*)(ws + OFF_SEGSUM);
    int*    node_inc  = (int*)(ws + OFF_NINC);
    int*    edge_mem  = (int*)(ws + OFF_EMEM);
    float4* item      = (float4*)(ws + OFF_ITEM);

    k_foldzero<<<ZERO_BYTES / 4 / 256, 256, 0, stream>>>(Ww, Wb, ea, vkhT, bl, (uint_t*)ws);
    k_logits<<<N_NODES / 32, 256, 0, stream>>>(x, vkhT, bl, node_idx, edge_idx,
                                               seg_size, node_cnt, logit);
    k_scan<<<2, 256, 0, stream>>>(node_cnt, node_ptr, seg_size, edge_ptr);
    k_fill<<<NUM_INC / 256, 256, 0, stream>>>(node_idx, edge_idx, node_ptr, edge_ptr,
                                              node_fill, edge_fill, node_inc, edge_mem);
    k_seg<<<NUM_EDGES / 256, 256, 0, stream>>>(edge_ptr, edge_mem, logit, seg_sum);
    k_pairs<<<NUM_INC / 256, 256, 0, stream>>>(node_inc, node_idx, edge_idx, edge_ptr,
                                               logit, seg_sum, item);
    k_aw_out<<<N_NODES, 256, 0, stream>>>(item, node_ptr, edge_mem, x, ow, ob, aw, out0);
}

// Round 17
// 364.026 us; speedup vs baseline: 1.3662x; 1.0101x over previous
//
#include <hip/hip_runtime.h>
#include <stdint.h>

#define N_NODES  8192
#define HIDDEN   256
#define HEADS    4
#define HEAD_DIM 64
#define NUM_EDGES 4096
#define NUM_INC  65536
#define LN_EPS   1e-5f

typedef unsigned int uint_t;
typedef float __attribute__((ext_vector_type(4))) f4v;

// Inputs fp32, OUTPUTS fp32 (r11-r16 verified, absmax 0.0156).
// Budget model: ~218us fixed harness poison/restore in the timed window;
// kernel share ~150us vs ~110us floor. This round: role-split k_aw_out
// (out0 blocks first, AW blocks after) + item-load software pipeline.

// ---------------- ws layout (bytes) ----------------
#define OFF_SEGSZ    0        // int [4096]   } zeroed by k_foldzero
#define OFF_NCNT     16384    // int [8192]   }
#define OFF_NFILL    49152    // int [8192]   }
#define OFF_EFILL    81920    // int [4096]   }
#define ZERO_BYTES   98304
#define OFF_VKH      98304    // float [4*256] transposed [h][k]
#define OFF_BL       102400   // float [pad]
#define OFF_LOGIT    102464   // float [8192*4]
#define OFF_NPTR     233536   // int [8193] (+pad)
#define OFF_EPTR     266320   // int [4097] (+pad)
#define OFF_SEGSUM   282720   // float [4096*4]
#define OFF_NINC     348256   // int [65536]
#define OFF_EMEM     610400   // int [65536]
#define OFF_ITEM     872544   // float4 [65536] = {attn, qb, qe, 0}

// K1: zero accumulators (96 blocks); blocks 0..3 also fold W_w/W_b with ea.
__global__ __launch_bounds__(256) void k_foldzero(const float* __restrict__ Ww,
                                                  const float* __restrict__ Wb,
                                                  const float* __restrict__ ea,
                                                  float* __restrict__ vkhT,
                                                  float* __restrict__ bl,
                                                  uint_t* __restrict__ zw) {
    int t = threadIdx.x, b = blockIdx.x;
    zw[b * 256 + t] = 0u;
    if (b < HEADS) {
        int k = t, h = b;
        float a = 0.f;
        for (int d = 0; d < HEAD_DIM; ++d)
            a += ea[h * HEAD_DIM + d] * Ww[(size_t)(h * HEAD_DIM + d) * HIDDEN + k];
        vkhT[h * HIDDEN + k] = a;
        if (k == 0) {
            float s = 0.f;
            for (int d = 0; d < HEAD_DIM; ++d)
                s += Wb[h * HEAD_DIM + d] * ea[h * HEAD_DIM + d];
            bl[h] = s;
        }
    }
}

// K2: logits (256 blocks x 32 nodes) + independent histogram atomics folded in.
__global__ __launch_bounds__(256) void k_logits(const float* __restrict__ x,
                                                const float* __restrict__ vkhT,
                                                const float* __restrict__ bl,
                                                const int* __restrict__ node_idx,
                                                const int* __restrict__ edge_idx,
                                                int* __restrict__ seg_size,
                                                int* __restrict__ node_cnt,
                                                float* __restrict__ logit) {
    __shared__ __align__(16) float xs[32 * HIDDEN];
    __shared__ __align__(16) float vs[HEADS * HIDDEN];
    __shared__ float bls[HEADS];
    int t = threadIdx.x, b = blockIdx.x;
    {
        int i = b * 256 + t;
        atomicAdd(&seg_size[edge_idx[i]], 1);
        atomicAdd(&node_cnt[node_idx[i]], 1);
    }
    float4* xsv = (float4*)xs;
    const float4* xg = (const float4*)(x + (size_t)b * 32 * HIDDEN);
    #pragma unroll
    for (int i = 0; i < 8; ++i) xsv[i * 256 + t] = xg[i * 256 + t];
    ((float4*)vs)[t] = ((const float4*)vkhT)[t];
    if (t < HEADS) bls[t] = bl[t];
    __syncthreads();
    if (t < 128) {
        int n = t >> 2, h = t & 3;
        const float4* xr = (const float4*)(xs + n * HIDDEN);
        const float4* vr = (const float4*)(vs + h * HIDDEN);
        float acc = bls[h];
        for (int k4 = 0; k4 < HIDDEN / 4; ++k4) {
            float4 xv = xr[k4], vv = vr[k4];
            acc += xv.x * vv.x + xv.y * vv.y + xv.z * vv.z + xv.w * vv.w;
        }
        logit[(b * 32 + n) * HEADS + h] = acc;
    }
}

// K3: exclusive scans
__global__ __launch_bounds__(256) void k_scan(const int* __restrict__ node_cnt, int* __restrict__ node_ptr,
                                              const int* __restrict__ seg_size, int* __restrict__ edge_ptr) {
    __shared__ int part[256];
    const int* cnt; int* ptr; int n;
    if (blockIdx.x == 0) { cnt = node_cnt; ptr = node_ptr; n = N_NODES; }
    else                 { cnt = seg_size; ptr = edge_ptr; n = NUM_EDGES; }
    int t = threadIdx.x, C = n / 256;
    int s = 0;
    for (int j = 0; j < C; ++j) s += cnt[t * C + j];
    part[t] = s;
    __syncthreads();
    if (t == 0) {
        int run = 0;
        for (int i = 0; i < 256; ++i) { int tmp = part[i]; part[i] = run; run += tmp; }
        ptr[n] = run;
    }
    __syncthreads();
    int run = part[t];
    for (int j = 0; j < C; ++j) { ptr[t * C + j] = run; run += cnt[t * C + j]; }
}

// K4: fill CSRs
__global__ void k_fill(const int* __restrict__ node_idx, const int* __restrict__ edge_idx,
                       const int* __restrict__ node_ptr, const int* __restrict__ edge_ptr,
                       int* __restrict__ node_fill, int* __restrict__ edge_fill,
                       int* __restrict__ node_inc, int* __restrict__ edge_mem) {
    int i = blockIdx.x * 256 + threadIdx.x;
    int n = node_idx[i], e = edge_idx[i];
    int p = node_ptr[n] + atomicAdd(&node_fill[n], 1);
    node_inc[p] = i;
    int q = edge_ptr[e] + atomicAdd(&edge_fill[e], 1);
    edge_mem[q] = n;
}

// K5: seg_sum by edge-parallel gather
__global__ __launch_bounds__(256) void k_seg(const int* __restrict__ edge_ptr,
                                             const int* __restrict__ edge_mem,
                                             const float* __restrict__ logit,
                                             float* __restrict__ seg_sum) {
    int e = blockIdx.x * 256 + threadIdx.x;
    int qb = edge_ptr[e], qe = edge_ptr[e + 1];
    float s0 = 0, s1 = 0, s2 = 0, s3 = 0;
    for (int q = qb; q < qe; ++q) {
        int j = edge_mem[q];
        s0 += __expf(logit[j * 4 + 0]);
        s1 += __expf(logit[j * 4 + 1]);
        s2 += __expf(logit[j * 4 + 2]);
        s3 += __expf(logit[j * 4 + 3]);
    }
    seg_sum[e * 4 + 0] = s0; seg_sum[e * 4 + 1] = s1;
    seg_sum[e * 4 + 2] = s2; seg_sum[e * 4 + 3] = s3;
}

// K6: aw_item[p] = {attn, qb, qe, 0} in node-CSR order
__global__ __launch_bounds__(256) void k_pairs(const int* __restrict__ node_inc,
                                               const int* __restrict__ node_idx,
                                               const int* __restrict__ edge_idx,
                                               const int* __restrict__ edge_ptr,
                                               const float* __restrict__ logit,
                                               const float* __restrict__ seg_sum,
                                               float4* __restrict__ item) {
    int p = blockIdx.x * 256 + threadIdx.x;
    int m = node_inc[p];
    int e = edge_idx[m];
    int qb = edge_ptr[e], qe = edge_ptr[e + 1];
    float a = 0.f;
    if (qe - qb >= 2) {
        int n = node_idx[m];
        float s = 0.f;
        #pragma unroll
        for (int h = 0; h < HEADS; ++h)
            s += __expf(logit[n * HEADS + h]) / seg_sum[e * HEADS + h];
        a = 0.25f * s;
    }
    float4 it;
    it.x = a;
    it.y = __int_as_float(qb);
    it.z = __int_as_float(qe);
    it.w = 0.f;
    item[p] = it;
}

// K7 (role-split, 8704 blocks): blocks 0..511 = out0 tiles (launch first,
// GEMM overlaps the AW store storm); blocks 512..8703 = AW row b-512.
__global__ __launch_bounds__(256) void k_aw_out(const float4* __restrict__ item,
                                                const int* __restrict__ node_ptr,
                                                const int* __restrict__ edge_mem,
                                                const float* __restrict__ x,
                                                const float* __restrict__ out_w,
                                                const float* __restrict__ out_b,
                                                float* __restrict__ AW,
                                                float* __restrict__ out0) {
    __shared__ __align__(16) float buf[N_NODES];   // 32 KB (row OR y[16][260])
    __shared__ float sr[16], mu_s[16], rs_s[16];
    int t = threadIdx.x, w = t >> 6, lane = t & 63;
    int b = blockIdx.x;

    if (b >= 512) {
        // ---- AW row i ----
        int i = b - 512;
        int pb = node_ptr[i], pe = node_ptr[i + 1];
        int p0 = pb + w;
        float4 nxt = (p0 < pe) ? item[p0] : make_float4(0.f, 0.f, 0.f, 0.f);
        float4* rowv = (float4*)buf;
        #pragma unroll
        for (int c = 0; c < 8; ++c) rowv[c * 256 + t] = make_float4(0.f, 0.f, 0.f, 0.f);
        __syncthreads();
        for (int p = p0; p < pe; p += 4) {         // 4 parallel wave chains
            float4 it = nxt;
            if (p + 4 < pe) nxt = item[p + 4];     // pipeline next chain load
            float a = it.x;
            if (a != 0.f) {
                int qb = __float_as_int(it.y), qe = __float_as_int(it.z);
                for (int q = qb + lane; q < qe; q += 64)
                    atomicAdd(&buf[edge_mem[q]], a);
            }
        }
        __syncthreads();
        if (t == 0) buf[i] = 0.f;                  // zero diagonal
        __syncthreads();
        f4v* dst = (f4v*)(AW + (size_t)i * N_NODES);
        #pragma unroll
        for (int c = 0; c < 8; ++c)
            __builtin_nontemporal_store(((const f4v*)rowv)[c * 256 + t], &dst[c * 256 + t]);
        return;
    }

    // ---- out0 tile rows [b*16, b*16+16) ----
    float (*y)[260] = (float (*)[260])buf;
    int R = b * 16;
    if (t < 16) {
        int n = R + t;
        int nb = node_ptr[n], ne = node_ptr[n + 1];
        float ws = 0.f;
        for (int p = nb; p < ne; ++p) ws += item[p].x;
        int c = ne - nb; if (c < 1) c = 1;
        sr[t] = ws / (float)c;
    }
    __syncthreads();
    #pragma unroll
    for (int r = 0; r < 16; ++r)
        y[r][t] = sr[r] * x[(size_t)(R + r) * HIDDEN + t];
    __syncthreads();
    float acc[16];
    float bias = out_b[t];
    #pragma unroll
    for (int r = 0; r < 16; ++r) acc[r] = bias;
    const float4* wr4 = (const float4*)(out_w + (size_t)t * HIDDEN);
    for (int j4 = 0; j4 < HIDDEN / 4; ++j4) {
        float4 wv = wr4[j4];
        #pragma unroll
        for (int r = 0; r < 16; ++r) {
            float4 yv = *(const float4*)&y[r][j4 * 4];
            acc[r] += yv.x * wv.x + yv.y * wv.y + yv.z * wv.z + yv.w * wv.w;
        }
    }
    __syncthreads();
    #pragma unroll
    for (int r = 0; r < 16; ++r) y[r][t] = acc[r];
    __syncthreads();
    #pragma unroll
    for (int rr = 0; rr < 4; ++rr) {
        int r = (w << 2) | rr;
        float v = y[r][lane] + y[r][lane + 64] + y[r][lane + 128] + y[r][lane + 192];
        #pragma unroll
        for (int off = 32; off; off >>= 1) v += __shfl_down(v, off, 64);
        float mu = __shfl(v, 0, 64) * (1.0f / HIDDEN);
        float d0 = y[r][lane] - mu, d1 = y[r][lane + 64] - mu;
        float d2 = y[r][lane + 128] - mu, d3 = y[r][lane + 192] - mu;
        float s2 = d0 * d0 + d1 * d1 + d2 * d2 + d3 * d3;
        #pragma unroll
        for (int off = 32; off; off >>= 1) s2 += __shfl_down(s2, off, 64);
        if (lane == 0) {
            mu_s[r] = mu;
            rs_s[r] = rsqrtf(s2 * (1.0f / HIDDEN) + LN_EPS);
        }
    }
    __syncthreads();
    #pragma unroll
    for (int r = 0; r < 16; ++r)
        out0[(size_t)(R + r) * HIDDEN + t] = (y[r][t] - mu_s[r]) * rs_s[r];
}

extern "C" void kernel_launch(void* const* d_in, const int* in_sizes, int n_in,
                              void* d_out, int out_size, void* d_ws, size_t ws_size,
                              hipStream_t stream) {
    const float* x        = (const float*)d_in[0];
    const int*   node_idx = (const int*)d_in[1];
    const int*   edge_idx = (const int*)d_in[2];
    const float* Ww       = (const float*)d_in[3];
    const float* Wb       = (const float*)d_in[4];
    const float* ea       = (const float*)d_in[5];
    const float* ow       = (const float*)d_in[6];
    const float* ob       = (const float*)d_in[7];
    float* out0 = (float*)d_out;
    float* aw   = out0 + (size_t)N_NODES * HIDDEN;

    char* ws = (char*)d_ws;
    int*    seg_size  = (int*)(ws + OFF_SEGSZ);
    int*    node_cnt  = (int*)(ws + OFF_NCNT);
    int*    node_fill = (int*)(ws + OFF_NFILL);
    int*    edge_fill = (int*)(ws + OFF_EFILL);
    float*  vkhT      = (float*)(ws + OFF_VKH);
    float*  bl        = (float*)(ws + OFF_BL);
    float*  logit     = (float*)(ws + OFF_LOGIT);
    int*    node_ptr  = (int*)(ws + OFF_NPTR);
    int*    edge_ptr  = (int*)(ws + OFF_EPTR);
    float*  seg_sum   = (float*)(ws + OFF_SEGSUM);
    int*    node_inc  = (int*)(ws + OFF_NINC);
    int*    edge_mem  = (int*)(ws + OFF_EMEM);
    float4* item      = (float4*)(ws + OFF_ITEM);

    k_foldzero<<<ZERO_BYTES / 4 / 256, 256, 0, stream>>>(Ww, Wb, ea, vkhT, bl, (uint_t*)ws);
    k_logits<<<N_NODES / 32, 256, 0, stream>>>(x, vkhT, bl, node_idx, edge_idx,
                                               seg_size, node_cnt, logit);
    k_scan<<<2, 256, 0, stream>>>(node_cnt, node_ptr, seg_size, edge_ptr);
    k_fill<<<NUM_INC / 256, 256, 0, stream>>>(node_idx, edge_idx, node_ptr, edge_ptr,
                                              node_fill, edge_fill, node_inc, edge_mem);
    k_seg<<<NUM_EDGES / 256, 256, 0, stream>>>(edge_ptr, edge_mem, logit, seg_sum);
    k_pairs<<<NUM_INC / 256, 256, 0, stream>>>(node_inc, node_idx, edge_idx, edge_ptr,
                                               logit, seg_sum, item);
    k_aw_out<<<N_NODES + 512, 256, 0, stream>>>(item, node_ptr, edge_mem, x, ow, ob, aw, out0);
}